// Round 4
// baseline (432.787 us; speedup 1.0000x reference)
//
#include <hip/hip_runtime.h>

#define EPS 1e-5f

constexpr int NB = 2, HQ = 272, WQ = 480, HH = 544, WH = 960, HF = 1088, WF = 1920;
constexpr int KSEL = 5000;                 // 80000/16
constexpr int NQ  = HQ * WQ;               // 130560 = 64*2040
constexpr int NEL = NB * NQ;               // 261120
constexpr int PHA_N = NB * HF * WF;        // 4177920
constexpr int FGR_BASE = PHA_N;            // floats into d_out
constexpr int REF_BASE = PHA_N * 4;        // pha(1) + fgr(3)
constexpr int TIE_CAP = 8192;

// topk fused-kernel geometry
constexpr int TKB = 128;                   // blocks (<=256 CUs -> co-resident)
constexpr int TKT = TKB * 256;             // total threads
constexpr int CH64 = NQ / 64;              // 2040 elements per hist chunk (<65536 for u16)
constexpr unsigned SYNC_MAGIC = 0x5A17C0DEu;

// ---- ws layout in 4-byte units ----
constexpr int OFF_H1      = 0;                    // 2*32768 (L1 hist, 15-bit bins)
constexpr int OFF_H2      = 65536;                // 2*131072 (L2 hist, 17-bit bins)
constexpr int OFF_META    = 327680;               // 16 ints
constexpr int OFF_TIECNT  = 327696;               // 2
constexpr int OFF_PCOUNT  = 327698;               // 1
constexpr int OFF_SYNC    = 327700;               // 8 u32: [0]=magic, [1..6]=barrier counters
constexpr int OFF_TIELIST = 327712;               // 2*TIE_CAP
constexpr int OFF_PLIST   = OFF_TIELIST + 2 * TIE_CAP;   // 344096, 10000 ints
constexpr int OFF_WB      = 354112;               // 64 floats (folded biases)
constexpr int OFF_YH      = 354176;               // NB*HH*WH*6 floats
constexpr int OFF_WP      = OFF_YH + NB * HH * WH * 6;   // bf16 MFMA weight frags

typedef short s8v __attribute__((ext_vector_type(8)));
typedef float f4v __attribute__((ext_vector_type(4)));

static __device__ __forceinline__ unsigned short f2bf(float x) {
    unsigned u = __float_as_uint(x);
    u += 0x7fffu + ((u >> 16) & 1u);
    return (unsigned short)(u >> 16);
}
static __device__ __forceinline__ unsigned pack2(float a, float b) {
    return (unsigned)f2bf(a) | ((unsigned)f2bf(b) << 16);
}

// Fold BN into weights and pack straight into MFMA B-fragment order (bf16).
__global__ void prepack_all(
    const float* __restrict__ w1, const float* __restrict__ g1, const float* __restrict__ b1,
    const float* __restrict__ m1, const float* __restrict__ v1,
    const float* __restrict__ w2, const float* __restrict__ g2, const float* __restrict__ b2,
    const float* __restrict__ m2, const float* __restrict__ v2,
    const float* __restrict__ w3, const float* __restrict__ g3, const float* __restrict__ b3,
    const float* __restrict__ m3, const float* __restrict__ v3,
    const float* __restrict__ w4, const float* __restrict__ b4,
    unsigned short* __restrict__ P, float* __restrict__ Wb)
{
    int idx = blockIdx.x * 256 + threadIdx.x;
    if (idx < 32256) {
        int j = idx & 7;
        int lane = (idx >> 3) & 63;
        int frag = idx >> 9;
        int li = lane & 15, g = lane >> 4;
        float val = 0.f;
        if (frag < 36) {                       // conv1: frag = (tap*2+ks)*2 + nt
            int nt = frag & 1, ks = (frag >> 1) & 1, tap = frag >> 2;
            int n = nt * 16 + li, k = ks * 32 + 8 * g + j;
            if (n < 24 && k < 42) val = w1[(tap * 42 + k) * 24 + n] * (g1[n] / sqrtf(v1[n] + EPS));
        } else if (frag < 45) {                // conv2
            int tap = frag - 36, k = 8 * g + j;
            if (k < 24) val = w2[(tap * 24 + k) * 16 + li] * (g2[li] / sqrtf(v2[li] + EPS));
        } else if (frag < 54) {                // conv3
            int tap = frag - 45, k = 8 * g + j;
            if (li < 12 && k < 22) val = w3[(tap * 22 + k) * 12 + li] * (g3[li] / sqrtf(v3[li] + EPS));
        } else {                               // conv4
            int tap = frag - 54, k = 8 * g + j;
            if (li < 4 && k < 12) val = w4[(tap * 12 + k) * 4 + li];
        }
        P[idx] = f2bf(val);
    } else {
        int o = idx - 32256;
        if (o < 24) { float s = g1[o] / sqrtf(v1[o] + EPS); Wb[o] = b1[o] - m1[o] * s; }
        else if (o < 40) { int q = o - 24; float s = g2[q] / sqrtf(v2[q] + EPS); Wb[o] = b2[q] - m2[q] * s; }
        else if (o < 52) { int q = o - 40; float s = g3[q] / sqrtf(v3[q] + EPS); Wb[o] = b3[q] - m3[q] * s; }
        else if (o < 56) Wb[o] = b4[o - 52];
    }
}

// ---------------- fused top-K selection: one kernel, manual grid barriers ----------------
static __device__ __forceinline__ void gbar(unsigned* sync, int id) {
    __syncthreads();
    if (threadIdx.x == 0) {
        __hip_atomic_fetch_add(&sync[id], 1u, __ATOMIC_ACQ_REL, __HIP_MEMORY_SCOPE_AGENT);
        while (__hip_atomic_load(&sync[id], __ATOMIC_ACQUIRE, __HIP_MEMORY_SCOPE_AGENT) < (unsigned)TKB)
            __builtin_amdgcn_s_sleep(2);
    }
    __syncthreads();
}

__global__ __launch_bounds__(256) void topk_all(const float* __restrict__ err,
                                                unsigned* __restrict__ ws,
                                                float* __restrict__ out)
{
    unsigned* H1 = ws + OFF_H1;
    unsigned* H2 = ws + OFF_H2;
    int* meta    = (int*)(ws + OFF_META);
    int* tieCnt  = (int*)(ws + OFF_TIECNT);
    int* pcount  = (int*)(ws + OFF_PCOUNT);
    int* tieList = (int*)(ws + OFF_TIELIST);
    int* plist   = (int*)(ws + OFF_PLIST);
    unsigned* sync = ws + OFF_SYNC;

    __shared__ unsigned lh[16384];      // 64 KB: u16-packed hist; reused as scan buffer
    __shared__ int ssel; __shared__ unsigned scum;
    int tid = threadIdx.x;
    int gtid = blockIdx.x * 256 + tid;

    // init gate (ws is poisoned 0xAA before every call)
    if (blockIdx.x == 0) {
        if (tid < 8) __hip_atomic_store(&sync[1 + tid], 0u, __ATOMIC_RELAXED, __HIP_MEMORY_SCOPE_AGENT);
        __syncthreads();
        if (tid == 0) __hip_atomic_store(&sync[0], SYNC_MAGIC, __ATOMIC_RELEASE, __HIP_MEMORY_SCOPE_AGENT);
    } else {
        if (tid == 0)
            while (__hip_atomic_load(&sync[0], __ATOMIC_ACQUIRE, __HIP_MEMORY_SCOPE_AGENT) != SYNC_MAGIC)
                __builtin_amdgcn_s_sleep(2);
        __syncthreads();
    }

    // Phase A: zero H1+H2 (327680 u32 = 81920 uint4) + meta/tieCnt/pcount
    {
        uint4 z; z.x = z.y = z.z = z.w = 0u;
        uint4* p4 = (uint4*)ws;
        for (int i = gtid; i < 81920; i += TKT) p4[i] = z;
        if (gtid < 19) ws[OFF_META + gtid] = 0u;
    }
    gbar(sync, 1);

    // Phase B: L1 hist (15-bit bins), LDS-privatized u16 (chunk=2040 -> exact)
    {
        int b = blockIdx.x >> 6, ch = blockIdx.x & 63;
        for (int i = tid; i < 16384; i += 256) lh[i] = 0u;
        __syncthreads();
        int base = b * NQ + ch * CH64;
        for (int i = tid; i < CH64; i += 256) {
            unsigned bin = __float_as_uint(err[base + i]) >> 17;
            atomicAdd(&lh[bin >> 1], 1u << ((bin & 1) * 16));
        }
        __syncthreads();
        unsigned* gh = H1 + b * 32768;
        for (int i = tid; i < 16384; i += 256) {
            unsigned w = lh[i];
            if (w & 0xFFFFu) atomicAdd(&gh[2 * i], w & 0xFFFFu);
            if (w >> 16)     atomicAdd(&gh[2 * i + 1], w >> 16);
        }
    }
    gbar(sync, 2);

    // Phase C: find 15-bit bin containing the K-th value (blocks 0,1)
    if (blockIdx.x < NB) {
        int b = blockIdx.x;
        const unsigned* h = H1 + b * 32768;
        unsigned* sf = lh;
        unsigned own = 0;
        {
            const uint4* hv = (const uint4*)(h + tid * 128);
            for (int i = 0; i < 32; i++) { uint4 v = hv[i]; own += v.x + v.y + v.z + v.w; }
        }
        sf[tid] = own; __syncthreads();
        for (int off = 1; off < 256; off <<= 1) {
            unsigned v = (tid + off < 256) ? sf[tid + off] : 0u;
            __syncthreads(); sf[tid] += v; __syncthreads();
        }
        if (sf[tid] >= (unsigned)KSEL && sf[tid] - own < (unsigned)KSEL) { ssel = tid; scum = sf[tid] - own; }
        __syncthreads();
        int chunk = ssel; unsigned cum = scum;
        unsigned own2 = (tid < 128) ? h[chunk * 128 + tid] : 0u;
        __syncthreads();
        sf[tid] = own2; __syncthreads();
        for (int off = 1; off < 256; off <<= 1) {
            unsigned v = (tid + off < 256) ? sf[tid + off] : 0u;
            __syncthreads(); sf[tid] += v; __syncthreads();
        }
        if (cum + sf[tid] >= (unsigned)KSEL && cum + sf[tid] - own2 < (unsigned)KSEL) {
            meta[b * 8 + 0] = chunk * 128 + tid;            // 15-bit L1 bin
            meta[b * 8 + 1] = (int)(cum + sf[tid] - own2);  // count strictly above bin
        }
    }
    gbar(sync, 3);

    // Phase D: L2 hist on remaining 17 bits (only keys in the selected bin)
    {
        int m0 = meta[0], m1 = meta[8];
        for (int i = gtid; i < NEL; i += TKT) {
            int b = (i >= NQ) ? 1 : 0;
            unsigned key = __float_as_uint(err[i]);
            if ((int)(key >> 17) == (b ? m1 : m0))
                atomicAdd(&H2[b * 131072 + (key & 0x1FFFFu)], 1u);
        }
    }
    gbar(sync, 4);

    // Phase E: find exact threshold key T + tie count R (blocks 0,1)
    if (blockIdx.x < NB) {
        int b = blockIdx.x;
        const unsigned* h = H2 + b * 131072;
        unsigned* sf = lh;
        unsigned own = 0;
        {
            const uint4* hv = (const uint4*)(h + tid * 512);
            for (int i = 0; i < 128; i++) { uint4 v = hv[i]; own += v.x + v.y + v.z + v.w; }
        }
        sf[tid] = own; __syncthreads();
        for (int off = 1; off < 256; off <<= 1) {
            unsigned v = (tid + off < 256) ? sf[tid + off] : 0u;
            __syncthreads(); sf[tid] += v; __syncthreads();
        }
        unsigned cum0 = (unsigned)meta[b * 8 + 1];
        if (cum0 + sf[tid] >= (unsigned)KSEL && cum0 + sf[tid] - own < (unsigned)KSEL) {
            ssel = tid; scum = cum0 + sf[tid] - own;
        }
        __syncthreads();
        int chunk = ssel; unsigned cum = scum;
        unsigned hi = h[chunk * 512 + 2 * tid + 1], lo = h[chunk * 512 + 2 * tid];
        unsigned own2 = hi + lo;
        __syncthreads();
        sf[tid] = own2; __syncthreads();
        for (int off = 1; off < 256; off <<= 1) {
            unsigned v = (tid + off < 256) ? sf[tid + off] : 0u;
            __syncthreads(); sf[tid] += v; __syncthreads();
        }
        if (cum + sf[tid] >= (unsigned)KSEL && cum + sf[tid] - own2 < (unsigned)KSEL) {
            unsigned cumo = cum + sf[tid] - own2;   // count above this thread's 2 bins
            int bl; int R;
            if (cumo + hi >= (unsigned)KSEL) { bl = 2 * tid + 1; R = KSEL - (int)cumo; }
            else { bl = 2 * tid; R = KSEL - (int)(cumo + hi); }
            unsigned low17 = (unsigned)(chunk * 512 + bl);
            meta[b * 8 + 2] = (int)(((unsigned)meta[b * 8 + 0] << 17) | low17);  // exact key T
            meta[b * 8 + 3] = R;                                                 // ties to take
        }
    }
    gbar(sync, 5);

    // Phase F: write ref map, collect strict-above patches + tie candidates
    {
        unsigned T0 = (unsigned)meta[2], T1 = (unsigned)meta[10];
        for (int i = gtid; i < NEL; i += TKT) {
            int b = (i >= NQ) ? 1 : 0;
            unsigned key = __float_as_uint(err[i]);
            unsigned T = b ? T1 : T0;
            float r = 0.f;
            if (key > T) {
                r = 1.0f;
                int n = atomicAdd(pcount, 1);
                plist[n] = i;
            } else if (key == T) {
                int n = atomicAdd(&tieCnt[b], 1);
                if (n < TIE_CAP) tieList[b * TIE_CAP + n] = i - b * NQ;
            }
            out[REF_BASE + i] = r;
        }
    }
    gbar(sync, 6);

    // Phase G: rank ties, take lowest-index R (blocks 0,1)
    if (blockIdx.x < NB) {
        int b = blockIdx.x;
        int n = tieCnt[b]; if (n > TIE_CAP) n = TIE_CAP;
        int R = meta[b * 8 + 3];
        unsigned T = (unsigned)meta[b * 8 + 2];
        float val = (T > 0u) ? 1.0f : 0.0f;   // ref = selected * (err > 0)
        for (int e = tid; e < n; e += 256) {
            int my = tieList[b * TIE_CAP + e];
            int rank = 0;
            for (int f = 0; f < n; f++) rank += (tieList[b * TIE_CAP + f] < my) ? 1 : 0;
            if (rank < R) {
                out[REF_BASE + b * NQ + my] = val;
                int q = atomicAdd(pcount, 1);
                plist[q] = b * NQ + my;
            }
        }
    }
}

// ---------------- half-res src_bgr (antialiased 4-tap bilinear down) ----------------
__global__ void yh_kernel(const float* __restrict__ src, const float* __restrict__ bgr,
                          float* __restrict__ yh) {
    int idx = blockIdx.x * 256 + threadIdx.x;
    if (idx >= NB * HH * WH) return;
    int hx = idx % WH; int t = idx / WH; int hy = t % HH; int b = t / HH;

    float wy[4]; int jy[4]; float sy = 0.f;
#pragma unroll
    for (int k = 0; k < 4; k++) {
        int j = 2 * hy - 1 + k;
        float w = (k == 0 || k == 3) ? 0.125f : 0.375f;
        if (j < 0 || j >= HF) { w = 0.f; j = 0; }
        jy[k] = j; wy[k] = w; sy += w;
    }
    float wx[4]; int jx[4]; float sx = 0.f;
#pragma unroll
    for (int k = 0; k < 4; k++) {
        int j = 2 * hx - 1 + k;
        float w = (k == 0 || k == 3) ? 0.125f : 0.375f;
        if (j < 0 || j >= WF) { w = 0.f; j = 0; }
        jx[k] = j; wx[k] = w; sx += w;
    }
    float inv = 1.f / (sy * sx);
    float acc[6] = {0.f, 0.f, 0.f, 0.f, 0.f, 0.f};
#pragma unroll
    for (int a = 0; a < 4; a++) {
#pragma unroll
        for (int c = 0; c < 4; c++) {
            float w = wy[a] * wx[c];
            int p = ((b * HF + jy[a]) * WF + jx[c]) * 3;
            acc[0] += w * src[p + 0]; acc[1] += w * src[p + 1]; acc[2] += w * src[p + 2];
            acc[3] += w * bgr[p + 0]; acc[4] += w * bgr[p + 1]; acc[5] += w * bgr[p + 2];
        }
    }
    float* Y = yh + (size_t)idx * 6;
#pragma unroll
    for (int j = 0; j < 6; j++) Y[j] = acc[j] * inv;
}

// ---------------- base 4x bilinear upsample, 4 px / thread, float4 stores ----------------
__global__ __launch_bounds__(256) void base_up4(const float* __restrict__ pha,
                                                const float* __restrict__ fgr,
                                                float* __restrict__ out) {
    int t = blockIdx.x * 256 + threadIdx.x;      // exactly PHA_N/4 threads
    int kx = t % 480;
    int rest = t / 480;
    int y = rest % HF; int b = rest / HF;

    int ky = y >> 2, ry = y & 3;
    int qy0; float wy0;
    if (ry == 0) { qy0 = ky - 1; wy0 = 0.375f; }
    else if (ry == 1) { qy0 = ky - 1; wy0 = 0.125f; }
    else if (ry == 2) { qy0 = ky; wy0 = 0.875f; }
    else { qy0 = ky; wy0 = 0.625f; }
    int qy1 = qy0 + 1; float wy1 = 1.f - wy0;
    if (qy0 < 0) qy0 = 0; if (qy1 > HQ - 1) qy1 = HQ - 1;

    int c0 = max(kx - 1, 0), c2 = min(kx + 1, WQ - 1);
    int r0 = (b * HQ + qy0) * WQ, r1 = (b * HQ + qy1) * WQ;

    float A = wy0 * pha[r0 + c0] + wy1 * pha[r1 + c0];
    float B = wy0 * pha[r0 + kx] + wy1 * pha[r1 + kx];
    float C = wy0 * pha[r0 + c2] + wy1 * pha[r1 + c2];
    float4 po;
    po.x = 0.375f * A + 0.625f * B;
    po.y = 0.125f * A + 0.875f * B;
    po.z = 0.875f * B + 0.125f * C;
    po.w = 0.625f * B + 0.375f * C;
    int oidx = (b * HF + y) * WF + kx * 4;
    *(float4*)(out + oidx) = po;

    float f[12];
#pragma unroll
    for (int j = 0; j < 3; j++) {
        float a = wy0 * fgr[(r0 + c0) * 3 + j] + wy1 * fgr[(r1 + c0) * 3 + j];
        float bb = wy0 * fgr[(r0 + kx) * 3 + j] + wy1 * fgr[(r1 + kx) * 3 + j];
        float c = wy0 * fgr[(r0 + c2) * 3 + j] + wy1 * fgr[(r1 + c2) * 3 + j];
        f[0 + j] = 0.375f * a + 0.625f * bb;
        f[3 + j] = 0.125f * a + 0.875f * bb;
        f[6 + j] = 0.875f * bb + 0.125f * c;
        f[9 + j] = 0.625f * bb + 0.375f * c;
    }
    float* fo = out + FGR_BASE + (size_t)oidx * 3;
    float4 s0, s1, s2;
    s0.x = f[0]; s0.y = f[1]; s0.z = f[2];  s0.w = f[3];
    s1.x = f[4]; s1.y = f[5]; s1.z = f[6];  s1.w = f[7];
    s2.x = f[8]; s2.y = f[9]; s2.z = f[10]; s2.w = f[11];
    *(float4*)(fo + 0) = s0; *(float4*)(fo + 4) = s1; *(float4*)(fo + 8) = s2;
}

// ---------------- per-patch refiner CNN via MFMA: 1 wave per patch ----------------
// Phase 0 stages the unique 5x5 quarter-res block (36 ch) into LDS once,
// then interpolates the 8x8x42 conv1 window from LDS (kills the 10x redundant
// global gather that made FETCH_SIZE = 52 MB).
__global__ __launch_bounds__(64) void patch_kernel(
    const float* __restrict__ src, const float* __restrict__ bgr,
    const float* __restrict__ pha, const float* __restrict__ fgr,
    const float* __restrict__ hid, const float* __restrict__ yh,
    const float* __restrict__ Wb, const unsigned short* __restrict__ WP,
    const int* __restrict__ plist, const int* __restrict__ pcount,
    float* __restrict__ out)
{
    if ((int)blockIdx.x >= *pcount) return;
    int pk = plist[blockIdx.x];
    int b = pk / NQ, pos = pk % NQ;
    int iy = pos / WQ, ix = pos % WQ;
    int lane = threadIdx.x;
    int g = lane >> 4, li = lane & 15;

    __shared__ __align__(16) unsigned short win[64 * 72];  // 9216 B
    __shared__ __align__(16) float uu[900];                // qs 3600 B; aliased as t1s (2880 B)
    unsigned short* t1s = (unsigned short*)uu;
    float* qs = uu;

    const s8v* WP1v = (const s8v*)WP;          // 36 frags
    const s8v* WP2v = WP1v + 36 * 64;          // 9
    const s8v* WP3v = WP2v + 9 * 64;           // 9
    const s8v* WP4v = WP3v + 9 * 64;           // 9

    // ---- Phase 0a: stage 5x5 quarter block [px][36] = [hid32 | pha | fgr3] ----
    {
        for (int t = lane; t < 200; t += 64) {
            int px = t >> 3, q = t & 7;
            int jy = px / 5, jx = px - jy * 5;
            int ry = min(max(iy - 2 + jy, 0), HQ - 1);
            int rx = min(max(ix - 2 + jx, 0), WQ - 1);
            float4 v = ((const float4*)(hid + ((size_t)((b * HQ + ry) * WQ + rx)) * 32))[q];
            float* d = qs + px * 36 + q * 4;
            d[0] = v.x; d[1] = v.y; d[2] = v.z; d[3] = v.w;
        }
        for (int t = lane; t < 100; t += 64) {
            int px = t >> 2, c = t & 3;
            int jy = px / 5, jx = px - jy * 5;
            int ry = min(max(iy - 2 + jy, 0), HQ - 1);
            int rx = min(max(ix - 2 + jx, 0), WQ - 1);
            int base = (b * HQ + ry) * WQ + rx;
            qs[px * 36 + 32 + c] = (c == 0) ? pha[base] : fgr[base * 3 + (c - 1)];
        }
    }
    __syncthreads();

    // ---- Phase 0b: conv1 input window [8][8][42] -> bf16 LDS (interp from qs) ----
    {
        int r = lane >> 3, c = lane & 7;
        int hy = iy * 2 - 3 + r, hx = ix * 2 - 3 + c;
        unsigned* wrow = (unsigned*)&win[lane * 72];
        if (hy < 0 || hy >= HH || hx < 0 || hx >= WH) {
#pragma unroll
            for (int q = 0; q < 32; q++) wrow[q] = 0u;
        } else {
            int ay = ((r - 4) >> 1) + 2;          // 0..3
            int ax = ((c - 4) >> 1) + 2;          // 0..3
            float wy0 = (hy & 1) ? 0.75f : 0.25f, wy1 = 1.f - wy0;
            float wx0 = (hx & 1) ? 0.75f : 0.25f, wx1 = 1.f - wx0;
            float w00 = wy0 * wx0, w01 = wy0 * wx1, w10 = wy1 * wx0, w11 = wy1 * wx1;
            const float* q00 = qs + (ay * 5 + ax) * 36;
            const float* q01 = q00 + 36;
            const float* q10 = q00 + 180;
            const float* q11 = q10 + 36;
#pragma unroll
            for (int q = 0; q < 8; q++) {
                float e0 = q00[q*4+0]*w00 + q01[q*4+0]*w01 + q10[q*4+0]*w10 + q11[q*4+0]*w11;
                float e1 = q00[q*4+1]*w00 + q01[q*4+1]*w01 + q10[q*4+1]*w10 + q11[q*4+1]*w11;
                float e2 = q00[q*4+2]*w00 + q01[q*4+2]*w01 + q10[q*4+2]*w10 + q11[q*4+2]*w11;
                float e3 = q00[q*4+3]*w00 + q01[q*4+3]*w01 + q10[q*4+3]*w10 + q11[q*4+3]*w11;
                wrow[q * 2]     = pack2(e0, e1);
                wrow[q * 2 + 1] = pack2(e2, e3);
            }
            float e32 = q00[32]*w00 + q01[32]*w01 + q10[32]*w10 + q11[32]*w11;
            float f0  = q00[33]*w00 + q01[33]*w01 + q10[33]*w10 + q11[33]*w11;
            float f1  = q00[34]*w00 + q01[34]*w01 + q10[34]*w10 + q11[34]*w11;
            float f2  = q00[35]*w00 + q01[35]*w01 + q10[35]*w10 + q11[35]*w11;
            wrow[16] = pack2(e32, f0);
            wrow[17] = pack2(f1, f2);
            const float* Y = yh + (size_t)((b * HH + hy) * WH + hx) * 6;
            wrow[18] = pack2(Y[0], Y[1]);
            wrow[19] = pack2(Y[2], Y[3]);
            wrow[20] = pack2(Y[4], Y[5]);
#pragma unroll
            for (int q = 21; q < 32; q++) wrow[q] = 0u;
        }
    }
    __syncthreads();

    // position -> 6x6 grid cell bases (shared by conv1 & conv3)
    int p0 = li, p1 = 16 + li, p2 = (32 + li > 35) ? 35 : 32 + li;
    int pr0 = (p0 * 171) >> 10, pc0 = p0 - pr0 * 6;
    int pr1 = (p1 * 171) >> 10, pc1 = p1 - pr1 * 6;
    int pr2m = (p2 * 171) >> 10, pc2m = p2 - pr2m * 6;
    int cb0 = pr0 * 8 + pc0, cb1 = pr1 * 8 + pc1, cb2 = pr2m * 8 + pc2m;

    // ---- conv1: [36,378] x [378,24] ----
    f4v a00 = {0,0,0,0}, a01 = {0,0,0,0}, a10 = {0,0,0,0},
        a11 = {0,0,0,0}, a20 = {0,0,0,0}, a21 = {0,0,0,0};
    {
        const unsigned short* r0 = &win[cb0 * 72 + g * 8];
        const unsigned short* r1 = &win[cb1 * 72 + g * 8];
        const unsigned short* r2 = &win[cb2 * 72 + g * 8];
#pragma unroll
        for (int tap = 0; tap < 9; tap++) {
            const int dr = tap / 3, dc = tap % 3;
            const int coff = (dr * 8 + dc) * 72;
#pragma unroll
            for (int ks = 0; ks < 2; ks++) {
                s8v av0 = *(const s8v*)(r0 + coff + ks * 32);
                s8v av1 = *(const s8v*)(r1 + coff + ks * 32);
                s8v av2 = *(const s8v*)(r2 + coff + ks * 32);
                s8v bv0 = WP1v[((tap * 2 + ks) * 2 + 0) * 64 + lane];
                s8v bv1 = WP1v[((tap * 2 + ks) * 2 + 1) * 64 + lane];
                a00 = __builtin_amdgcn_mfma_f32_16x16x32_bf16(av0, bv0, a00, 0, 0, 0);
                a01 = __builtin_amdgcn_mfma_f32_16x16x32_bf16(av0, bv1, a01, 0, 0, 0);
                a10 = __builtin_amdgcn_mfma_f32_16x16x32_bf16(av1, bv0, a10, 0, 0, 0);
                a11 = __builtin_amdgcn_mfma_f32_16x16x32_bf16(av1, bv1, a11, 0, 0, 0);
                a20 = __builtin_amdgcn_mfma_f32_16x16x32_bf16(av2, bv0, a20, 0, 0, 0);
                a21 = __builtin_amdgcn_mfma_f32_16x16x32_bf16(av2, bv1, a21, 0, 0, 0);
            }
        }
    }
    // epi1 -> t1s[pos][ch], ch 24..31 exact zeros (zero B cols + zero bias)
    {
        float b1n0 = Wb[li];
        float b1n1 = (li < 8) ? Wb[16 + li] : 0.f;
#pragma unroll
        for (int r = 0; r < 4; r++) {
            int p = 4 * g + r;
            t1s[p * 40 + li]        = f2bf(fmaxf(a00[r] + b1n0, 0.f));
            t1s[p * 40 + 16 + li]   = f2bf(fmaxf(a01[r] + b1n1, 0.f));
            int pp = 16 + p;
            t1s[pp * 40 + li]       = f2bf(fmaxf(a10[r] + b1n0, 0.f));
            t1s[pp * 40 + 16 + li]  = f2bf(fmaxf(a11[r] + b1n1, 0.f));
            int p2r = 32 + p;
            if (p2r < 36) {
                t1s[p2r * 40 + li]      = f2bf(fmaxf(a20[r] + b1n0, 0.f));
                t1s[p2r * 40 + 16 + li] = f2bf(fmaxf(a21[r] + b1n1, 0.f));
            }
        }
    }
    __syncthreads();

    // ---- conv2: [16,216] x [216,16] ----
    f4v c2 = {0,0,0,0};
    {
        int pr = li >> 2, pc = li & 3;
#pragma unroll
        for (int tap = 0; tap < 9; tap++) {
            const int dr = tap / 3, dc = tap % 3;
            int cell = (pr + dr) * 6 + pc + dc;
            s8v av = *(const s8v*)&t1s[cell * 40 + g * 8];
            c2 = __builtin_amdgcn_mfma_f32_16x16x32_bf16(av, WP2v[tap * 64 + lane], c2, 0, 0, 0);
        }
    }
    __syncthreads();
    // epi2: nearest-up2 t2 into win[cell][li] (stride 40); src/bgr chans + zero pads
    {
        float b2v = Wb[24 + li];
#pragma unroll
        for (int r = 0; r < 4; r++) {
            int p = 4 * g + r;
            unsigned short hv = f2bf(fmaxf(c2[r] + b2v, 0.f));
            int r0 = (p >> 2) * 2, c0 = (p & 3) * 2;
            win[(r0 * 8 + c0) * 40 + li]           = hv;
            win[(r0 * 8 + c0 + 1) * 40 + li]       = hv;
            win[((r0 + 1) * 8 + c0) * 40 + li]     = hv;
            win[((r0 + 1) * 8 + c0 + 1) * 40 + li] = hv;
        }
        int rr = lane >> 3, cc = lane & 7;
        int fy = iy * 4 - 2 + rr, fx = ix * 4 - 2 + cc;
        unsigned* wp3 = (unsigned*)&win[lane * 40];
        if (fy >= 0 && fy < HF && fx >= 0 && fx < WF) {
            const float* sp = src + ((size_t)(b * HF + fy) * WF + fx) * 3;
            const float* bp = bgr + ((size_t)(b * HF + fy) * WF + fx) * 3;
            wp3[8]  = pack2(sp[0], sp[1]);
            wp3[9]  = pack2(sp[2], bp[0]);
            wp3[10] = pack2(bp[1], bp[2]);
        } else {
            wp3[8] = 0u; wp3[9] = 0u; wp3[10] = 0u;
        }
        wp3[11] = 0u; wp3[12] = 0u; wp3[13] = 0u; wp3[14] = 0u; wp3[15] = 0u;
        // zero t3 pad cols 16..31 (t1 data dead now)
        for (int idx = lane; idx < 36 * 8; idx += 64) {
            int row = idx >> 3;
            ((unsigned*)t1s)[row * 20 + 8 + (idx & 7)] = 0u;
        }
    }
    __syncthreads();

    // ---- conv3: [36,198] x [198,12] ----
    f4v c30 = {0,0,0,0}, c31 = {0,0,0,0}, c32 = {0,0,0,0};
    {
        const unsigned short* r0 = &win[cb0 * 40 + g * 8];
        const unsigned short* r1 = &win[cb1 * 40 + g * 8];
        const unsigned short* r2 = &win[cb2 * 40 + g * 8];
#pragma unroll
        for (int tap = 0; tap < 9; tap++) {
            const int dr = tap / 3, dc = tap % 3;
            const int coff = (dr * 8 + dc) * 40;
            s8v bv = WP3v[tap * 64 + lane];
            c30 = __builtin_amdgcn_mfma_f32_16x16x32_bf16(*(const s8v*)(r0 + coff), bv, c30, 0, 0, 0);
            c31 = __builtin_amdgcn_mfma_f32_16x16x32_bf16(*(const s8v*)(r1 + coff), bv, c31, 0, 0, 0);
            c32 = __builtin_amdgcn_mfma_f32_16x16x32_bf16(*(const s8v*)(r2 + coff), bv, c32, 0, 0, 0);
        }
    }
    __syncthreads();
    // epi3 -> t3 (= t1s) [pos][ch], ch 12..15 exact zeros
    {
        float b3v = (li < 12) ? Wb[40 + li] : 0.f;
#pragma unroll
        for (int r = 0; r < 4; r++) {
            int p = 4 * g + r;
            t1s[p * 40 + li]        = f2bf(fmaxf(c30[r] + b3v, 0.f));
            t1s[(16 + p) * 40 + li] = f2bf(fmaxf(c31[r] + b3v, 0.f));
            int p2r = 32 + p;
            if (p2r < 36) t1s[p2r * 40 + li] = f2bf(fmaxf(c32[r] + b3v, 0.f));
        }
    }
    __syncthreads();

    // ---- conv4: [16,108] x [108,4] (no relu) + scatter ----
    f4v c4 = {0,0,0,0};
    {
        int pr = li >> 2, pc = li & 3;
#pragma unroll
        for (int tap = 0; tap < 9; tap++) {
            const int dr = tap / 3, dc = tap % 3;
            int cell = (pr + dr) * 6 + pc + dc;
            s8v av = *(const s8v*)&t1s[cell * 40 + g * 8];
            c4 = __builtin_amdgcn_mfma_f32_16x16x32_bf16(av, WP4v[tap * 64 + lane], c4, 0, 0, 0);
        }
    }
    if (li < 4) {
        float b4v = Wb[52 + li];
#pragma unroll
        for (int r = 0; r < 4; r++) {
            int p = 4 * g + r;
            int prow = p >> 2, pcol = p & 3;
            float v = c4[r] + b4v;
            int fidx = (b * HF + iy * 4 + prow) * WF + ix * 4 + pcol;
            if (li == 0) out[fidx] = v;
            else out[FGR_BASE + (size_t)fidx * 3 + (li - 1)] = v;
        }
    }
}

extern "C" void kernel_launch(void* const* d_in, const int* in_sizes, int n_in,
                              void* d_out, int out_size, void* d_ws, size_t ws_size,
                              hipStream_t stream)
{
    const float* src = (const float*)d_in[0];
    const float* bgr = (const float*)d_in[1];
    const float* pha = (const float*)d_in[2];
    const float* fgr = (const float*)d_in[3];
    const float* err = (const float*)d_in[4];
    const float* hid = (const float*)d_in[5];
    const float* w1 = (const float*)d_in[6];
    const float* g1 = (const float*)d_in[7];
    const float* b1 = (const float*)d_in[8];
    const float* m1 = (const float*)d_in[9];
    const float* v1 = (const float*)d_in[10];
    const float* w2 = (const float*)d_in[11];
    const float* g2 = (const float*)d_in[12];
    const float* b2 = (const float*)d_in[13];
    const float* m2 = (const float*)d_in[14];
    const float* v2 = (const float*)d_in[15];
    const float* w3 = (const float*)d_in[16];
    const float* g3 = (const float*)d_in[17];
    const float* b3 = (const float*)d_in[18];
    const float* m3 = (const float*)d_in[19];
    const float* v3 = (const float*)d_in[20];
    const float* w4 = (const float*)d_in[21];
    const float* b4 = (const float*)d_in[22];

    float* out = (float*)d_out;
    unsigned* ws = (unsigned*)d_ws;
    float* wsf = (float*)d_ws;
    int* plist   = (int*)(ws + OFF_PLIST);
    int* pcount  = (int*)(ws + OFF_PCOUNT);
    float* Wb = wsf + OFF_WB;
    float* yh = wsf + OFF_YH;
    unsigned short* WP = (unsigned short*)(wsf + OFF_WP);

    prepack_all<<<127, 256, 0, stream>>>(w1, g1, b1, m1, v1, w2, g2, b2, m2, v2,
                                         w3, g3, b3, m3, v3, w4, b4, WP, Wb);
    topk_all<<<TKB, 256, 0, stream>>>(err, ws, out);
    yh_kernel<<<(NB * HH * WH + 255) / 256, 256, 0, stream>>>(src, bgr, yh);
    base_up4<<<PHA_N / 4 / 256, 256, 0, stream>>>(pha, fgr, out);
    patch_kernel<<<NB * KSEL, 64, 0, stream>>>(src, bgr, pha, fgr, hid, yh, Wb, WP,
                                               plist, pcount, out);
}